// Round 8
// baseline (358.571 us; speedup 1.0000x reference)
//
#include <hip/hip_runtime.h>
#include <math.h>

// Problem constants (B=1, LAYERS=33, HEADS=20, SEQ=512)
#define SEQ   512
#define NF    660
#define CROP  510
#define EOSI  2
#define RT    16           // rows per block (pass1)
#define GH    20           // heads per group (pass1)
#define NT_   32           // row tiles
#define NG    33           // head groups

typedef float f4 __attribute__((ext_vector_type(4)));
typedef float f2 __attribute__((ext_vector_type(2)));

// barrier that waits only LDS ops -- keeps global-load prefetch in flight
#define BARRIER_LGKM() asm volatile("s_waitcnt lgkmcnt(0)\n\ts_barrier" ::: "memory")

// load 4 rows (8 x f4) of head f at rows row0..row0+3
#define LOADP8(buf, f) do {                                                   \
    const float* _b = A + ((size_t)(f) << 18) + ((size_t)row0 << 9);          \
    buf[0] = *(const f4*)(_b + 4 * lane);                                     \
    buf[1] = *(const f4*)(_b + 256 + 4 * lane);                               \
    buf[2] = *(const f4*)(_b + 512 + 4 * lane);                               \
    buf[3] = *(const f4*)(_b + 768 + 4 * lane);                               \
    buf[4] = *(const f4*)(_b + 1024 + 4 * lane);                              \
    buf[5] = *(const f4*)(_b + 1280 + 4 * lane);                              \
    buf[6] = *(const f4*)(_b + 1536 + 4 * lane);                              \
    buf[7] = *(const f4*)(_b + 1792 + 4 * lane);                              \
} while (0)

// consume 4 rows of head h: wa_acc += wf*v; rowsum -> shfl -> rowstage (LDS);
// colsum partial -> 8 LDS atomic adds. NO barrier, NO global store.
#define COMP8A(buf, wf, h) do {                                               \
    float cacc[8] = {0, 0, 0, 0, 0, 0, 0, 0};                                 \
    _Pragma("unroll")                                                         \
    for (int rr = 0; rr < 4; ++rr) {                                          \
        const float mi = mrow[rr];                                            \
        f4 x0 = buf[2 * rr], x1 = buf[2 * rr + 1];                            \
        float vals[8] = {x0[0], x0[1], x0[2], x0[3],                          \
                         x1[0], x1[1], x1[2], x1[3]};                         \
        float rs = 0.f;                                                       \
        _Pragma("unroll")                                                     \
        for (int e = 0; e < 8; ++e) {                                         \
            const float v = vals[e];                                          \
            wa_acc[rr][e] += (wf) * v;                                        \
            rs += mskv[e] * v;                                                \
            cacc[e] += mi * v;                                                \
        }                                                                     \
        _Pragma("unroll")                                                     \
        for (int off = 32; off > 0; off >>= 1)                                \
            rs += __shfl_down(rs, off, 64);                                   \
        if (lane == 0) rowstage[h][wave * 4 + rr] = rs;                       \
    }                                                                         \
    _Pragma("unroll")                                                         \
    for (int e = 0; e < 8; ++e)                                               \
        atomicAdd(&colstage[h][(e >> 2) * 256 + 4 * lane + (e & 3)], cacc[e]); \
} while (0)

// ---------------- Pass 1: stream 692MB once; barrier-free hot loop ----------
// grid (32 row-tiles, 33 head-groups), block 256 (4 waves).
// Cross-wave col-sum via LDS atomicAdd (ds_add_f32, no-return) -> no lockstep.
// LDS 43.3 KB -> 3 blocks/CU = 12 waves/CU, all sliding independently.
__global__ __launch_bounds__(256) void pass1_kernel(
    const float* __restrict__ A, const int* __restrict__ tokens,
    const float* __restrict__ weight,
    float* __restrict__ WApart, float* __restrict__ rowsum, float* __restrict__ colpart)
{
    __shared__ float msk[SEQ];                // 2 KB
    __shared__ float colstage[GH][SEQ];       // 40 KB accumulated via ds_add
    __shared__ float rowstage[GH][RT];        // 1.25 KB

    const int t = blockIdx.x, g = blockIdx.y;
    const int tid = threadIdx.x, wave = tid >> 6, lane = tid & 63;
    const int fbase = g * GH;

    for (int j = tid; j < SEQ; j += 256)
        msk[j] = (j >= 1 && j <= SEQ - 2 && tokens[j] != EOSI) ? 1.f : 0.f;
    {   // zero colstage (20*512 floats = 2560 f4)
        f4* cz = (f4*)&colstage[0][0];
        #pragma unroll
        for (int it = 0; it < 10; ++it)
            cz[it * 256 + tid] = (f4){0.f, 0.f, 0.f, 0.f};
    }
    __syncthreads();   // once, before the hot loop

    float mskv[8];
    #pragma unroll
    for (int e = 0; e < 8; ++e)
        mskv[e] = msk[(e >> 2) * 256 + 4 * lane + (e & 3)];

    const int row0 = t * RT + wave * 4;
    const float mrow[4] = {msk[row0], msk[row0 + 1], msk[row0 + 2], msk[row0 + 3]};

    float wa_acc[4][8];
    #pragma unroll
    for (int r = 0; r < 4; ++r)
        #pragma unroll
        for (int e = 0; e < 8; ++e) wa_acc[r][e] = 0.f;

    f4 bufA[8], bufB[8];
    LOADP8(bufA, fbase);                      // prime

    #pragma unroll 1
    for (int hh = 0; hh < 10; ++hh) {
        const int h0 = 2 * hh, h1 = h0 + 1;
        LOADP8(bufB, fbase + h1);             // next head in flight
        COMP8A(bufA, weight[fbase + h0], h0);
        if (hh < 9) LOADP8(bufA, fbase + h0 + 2);
        COMP8A(bufB, weight[fbase + h1], h1);
    }

    BARRIER_LGKM();   // all waves' ds_adds + rowstage writes complete

    // ---- flush colstage -> colpart: 20 heads x 512 cols contiguous (40 KB)
    {
        float* __restrict__ dst = colpart + ((size_t)t * NF + fbase) * SEQ;
        const float* __restrict__ src = &colstage[0][0];
        #pragma unroll
        for (int it = 0; it < 10; ++it) {
            const int fl = (it * 256 + tid) * 4;
            *(f4*)(dst + fl) = *(const f4*)(src + fl);
        }
    }
    // ---- flush rowstage -> rowsum (16 consecutive floats per head)
    #pragma unroll
    for (int it = 0; it < 2; ++it) {
        const int e = it * 256 + tid;
        if (e < GH * RT) {
            const int h = e >> 4, r = e & 15;
            rowsum[((size_t)(fbase + h) << 9) + t * RT + r] = rowstage[h][r];
        }
    }
    // ---- flush WApart (write-once, float4 coalesced)
    float* __restrict__ wp = WApart + (size_t)g * SEQ * SEQ;
    #pragma unroll
    for (int rr = 0; rr < 4; ++rr) {
        f4 o0 = {wa_acc[rr][0], wa_acc[rr][1], wa_acc[rr][2], wa_acc[rr][3]};
        f4 o1 = {wa_acc[rr][4], wa_acc[rr][5], wa_acc[rr][6], wa_acc[rr][7]};
        *(f4*)(wp + ((size_t)(row0 + rr) << 9) + 4 * lane) = o0;
        *(f4*)(wp + ((size_t)(row0 + rr) << 9) + 256 + 4 * lane) = o1;
    }
}

// ---------------- Kernel 2 (merged): WA-reduce + per-head a1/a12/scale --------
__global__ __launch_bounds__(512) void kernel2(
    const float* __restrict__ WApart, float* __restrict__ WA,
    const float* __restrict__ rowsum, const float* __restrict__ colpart,
    const int* __restrict__ tokens, const float* __restrict__ weight,
    float* __restrict__ a1, float* __restrict__ sfac)
{
    __shared__ float part[8];
    const int b = blockIdx.x, tid = threadIdx.x;
    if (b < 128) {
        const size_t idx4 = (size_t)b * 512 + tid;     // float4 index, 65536 total
        f4 a = *(const f4*)(WApart + 4 * idx4);
        #pragma unroll 8
        for (int g = 1; g < NG; ++g) {
            f4 x = *(const f4*)(WApart + (size_t)g * (SEQ * SEQ) + 4 * idx4);
            a += x;
        }
        *(f4*)(WA + 4 * idx4) = a;
    } else {
        const int f = b - 128, j = tid;
        float cs = 0.f;
        #pragma unroll 8
        for (int t = 0; t < NT_; ++t)
            cs += colpart[((size_t)t * NF + f) * SEQ + j];
        const float m = (j >= 1 && j <= SEQ - 2 && tokens[j] != EOSI) ? 1.f : 0.f;
        const float v = m * (rowsum[((size_t)f << 9) + j] + cs);
        a1[((size_t)f << 9) + j] = v;
        float s = v;
        #pragma unroll
        for (int off = 32; off > 0; off >>= 1)
            s += __shfl_down(s, off, 64);
        const int wave = tid >> 6, lane = tid & 63;
        if (lane == 0) part[wave] = s;
        __syncthreads();
        if (tid == 0) {
            float a12 = 0.f;
            #pragma unroll
            for (int k = 0; k < 8; ++k) a12 += part[k];
            sfac[f] = weight[f] / a12;
        }
    }
}

// ---------------- Pass 3: rank-660 outer-product + WA + sigmoid ----------------
// grid (32,32) = 1024 blocks; 16x16 output tile, 1 output/thread; 32-f chunks
__global__ __launch_bounds__(256) void pass3_kernel(
    const float* __restrict__ WA, const float* __restrict__ a1,
    const float* __restrict__ sfac, const int* __restrict__ tokens,
    const float* __restrict__ bias, float* __restrict__ out)
{
    const int TI = blockIdx.y * 16;
    const int TJ = blockIdx.x * 16;
    const int tid = threadIdx.x;
    const int tx = tid & 15, ty = tid >> 4;

    __shared__ float u_s[32][17];
    __shared__ float v_s[32][17];

    float acc = 0.f;

    for (int f0 = 0; f0 < NF; f0 += 32) {
        #pragma unroll
        for (int c = 0; c < 4; ++c) {
            const int e = c * 256 + tid;        // 0..1023
            const int arr = e >> 9, ff = (e >> 4) & 31, ii = e & 15;
            const int f = f0 + ff;
            float val = 0.f;
            if (f < NF) {
                if (arr == 0) {
                    int Iu = TI + 1 + ii; if (Iu > SEQ - 1) Iu = SEQ - 1;
                    val = a1[((size_t)f << 9) + Iu] * sfac[f];
                } else {
                    int Ju = TJ + 1 + ii; if (Ju > SEQ - 1) Ju = SEQ - 1;
                    val = a1[((size_t)f << 9) + Ju];
                }
            }
            if (arr == 0) u_s[ff][ii] = val; else v_s[ff][ii] = val;
        }
        __syncthreads();
        #pragma unroll
        for (int ff = 0; ff < 32; ++ff)
            acc += u_s[ff][ty] * v_s[ff][tx];
        __syncthreads();
    }

    const int i = TI + ty, j = TJ + tx;
    if (i < CROP && j < CROP) {
        const int I = i + 1, J = j + 1;
        const float mi = (tokens[I] != EOSI) ? 1.f : 0.f;
        const float mj = (tokens[J] != EOSI) ? 1.f : 0.f;
        const float first = mi * mj * (WA[((size_t)I << 9) + J] + WA[((size_t)J << 9) + I]);
        const float logit = first - acc + bias[0];
        out[(size_t)i * CROP + j] = 1.f / (1.f + expf(-logit));
    }
}

extern "C" void kernel_launch(void* const* d_in, const int* in_sizes, int n_in,
                              void* d_out, int out_size, void* d_ws, size_t ws_size,
                              hipStream_t stream) {
    const int*   tokens = (const int*)d_in[0];
    const float* A      = (const float*)d_in[1];
    const float* weight = (const float*)d_in[2];
    const float* bias   = (const float*)d_in[3];
    float* out = (float*)d_out;

    // workspace (floats), all write-once, no zeroing:
    // WApart[33*512*512] | colpart[32*660*512] | WA[512*512] | rowsum[660*512] | a1[660*512] | sfac[660]
    float* WApart  = (float*)d_ws;
    float* colpart = WApart + (size_t)NG * SEQ * SEQ;
    float* WA      = colpart + (size_t)NT_ * NF * SEQ;
    float* rowsum  = WA + (size_t)SEQ * SEQ;
    float* a1      = rowsum + (size_t)NF * SEQ;
    float* sfac    = a1 + (size_t)NF * SEQ;

    dim3 g1(NT_, NG);   // 32 x 33
    pass1_kernel<<<g1, 256, 0, stream>>>(A, tokens, weight, WApart, rowsum, colpart);

    kernel2<<<128 + NF, 512, 0, stream>>>(WApart, WA, rowsum, colpart, tokens, weight, a1, sfac);

    dim3 g3(32, 32);
    pass3_kernel<<<g3, 256, 0, stream>>>(WA, a1, sfac, tokens, bias, out);
}

// Round 9
// 243.108 us; speedup vs baseline: 1.4749x; 1.4749x over previous
//
#include <hip/hip_runtime.h>
#include <math.h>

// Problem constants (B=1, LAYERS=33, HEADS=20, SEQ=512)
#define SEQ   512
#define NF    660
#define CROP  510
#define EOSI  2
#define RT    16           // rows per block (pass1)
#define GH    20           // heads per group (pass1)
#define NT_   32           // row tiles
#define NG    33           // head groups

typedef float f4 __attribute__((ext_vector_type(4)));
typedef float f2 __attribute__((ext_vector_type(2)));

// barrier that waits only LDS ops -- keeps global-load prefetch in flight
#define BARRIER_LGKM() asm volatile("s_waitcnt lgkmcnt(0)\n\ts_barrier" ::: "memory")

// load one row-pair (2 rows x 2 float4) of head f starting at absolute row prow
#define LOADP(buf, f, prow) do {                                              \
    const float* _b = A + ((size_t)(f) << 18) + ((size_t)(prow) << 9);        \
    buf[0] = *(const f4*)(_b + 4 * lane);                                     \
    buf[1] = *(const f4*)(_b + 256 + 4 * lane);                               \
    buf[2] = *(const f4*)(_b + 512 + 4 * lane);                               \
    buf[3] = *(const f4*)(_b + 768 + 4 * lane);                               \
} while (0)

// consume one row-pair; row sums -> LDS rowstage (no global store in hot loop)
#define COMP(buf, wf, cacc, POFF, h) do {                                     \
    _Pragma("unroll")                                                         \
    for (int rr = 0; rr < 2; ++rr) {                                          \
        const float mi = mrow[(POFF) * 2 + rr];                               \
        f4 x0 = buf[2 * rr], x1 = buf[2 * rr + 1];                            \
        float vals[8] = {x0[0], x0[1], x0[2], x0[3],                          \
                         x1[0], x1[1], x1[2], x1[3]};                         \
        float rs = 0.f;                                                       \
        _Pragma("unroll")                                                     \
        for (int e = 0; e < 8; ++e) {                                         \
            const float v = vals[e];                                          \
            wa_acc[(POFF) * 2 + rr][e] += (wf) * v;                           \
            rs += mskv[e] * v;                                                \
            cacc[e] += mi * v;                                                \
        }                                                                     \
        _Pragma("unroll")                                                     \
        for (int off = 32; off > 0; off >>= 1)                                \
            rs += __shfl_down(rs, off, 64);                                   \
        if (lane == 0) rowstage[h][wave * 4 + (POFF) * 2 + rr] = rs;          \
    }                                                                         \
} while (0)

// ---------------- Pass 1: stream 692MB once at 16 waves/CU ----------------
// grid (32 row-tiles, 33 head-groups), block 256 (4 waves).
// VGPR <= 128 (two 4xf4 buffers) AND LDS 39.25 KB -> 4 blocks/CU = 16 waves/CU.
// Hot loop: loads + FMA + shfl + LDS only; colstage flushed twice (h=10, end),
// each flush fully between barriers so no COMP ever waits on a store.
__global__ __launch_bounds__(256, 4) void pass1_kernel(
    const float* __restrict__ A, const int* __restrict__ tokens,
    const float* __restrict__ weight,
    float* __restrict__ WApart, float* __restrict__ rowsum, float* __restrict__ colpart)
{
    __shared__ float msk[SEQ];                // 2 KB
    __shared__ float col_lds[2][4][SEQ];      // 16 KB per-head ping-pong
    __shared__ float colstage[10][SEQ];       // 20 KB (10 slots, double-flushed)
    __shared__ float rowstage[GH][RT];        // 1.25 KB

    const int t = blockIdx.x, g = blockIdx.y;
    const int tid = threadIdx.x, wave = tid >> 6, lane = tid & 63;
    const int fbase = g * GH;

    for (int j = tid; j < SEQ; j += 256)
        msk[j] = (j >= 1 && j <= SEQ - 2 && tokens[j] != EOSI) ? 1.f : 0.f;
    BARRIER_LGKM();

    float mskv[8];
    #pragma unroll
    for (int e = 0; e < 8; ++e)
        mskv[e] = msk[(e >> 2) * 256 + 4 * lane + (e & 3)];

    const int row0 = t * RT + wave * 4;
    const float mrow[4] = {msk[row0], msk[row0 + 1], msk[row0 + 2], msk[row0 + 3]};

    float wa_acc[4][8];
    #pragma unroll
    for (int r = 0; r < 4; ++r)
        #pragma unroll
        for (int e = 0; e < 8; ++e) wa_acc[r][e] = 0.f;

    f4 bufA[4], bufB[4];
    LOADP(bufA, fbase, row0);                 // prime

    #pragma unroll 1
    for (int h = 0; h < GH; ++h) {
        const int f = fbase + h;
        const float wf = weight[f];
        float cacc[8] = {0, 0, 0, 0, 0, 0, 0, 0};

        LOADP(bufB, f, row0 + 2);             // this head, pair1
        COMP(bufA, wf, cacc, 0, h);
        if (h < GH - 1) LOADP(bufA, f + 1, row0);   // next head, pair0
        COMP(bufB, wf, cacc, 1, h);

        // scatter per-wave col partials, then cross-wave combine into colstage
        const int pp = h & 1;
        #pragma unroll
        for (int e = 0; e < 8; ++e)
            col_lds[pp][wave][(e >> 2) * 256 + 4 * lane + (e & 3)] = cacc[e];
        BARRIER_LGKM();

        if (h == 10) {
            // flush heads 0..9 (slots 0..9) -> colpart; extra barrier so slot
            // reuse (h=10 writes slot 0) can't race the flush's ds_reads
            float* __restrict__ dst = colpart + ((size_t)t * NF + fbase) * SEQ;
            const float* __restrict__ src = &colstage[0][0];
            #pragma unroll
            for (int it = 0; it < 5; ++it) {
                const int fl = (it * 256 + tid) * 4;
                *(f4*)(dst + fl) = *(const f4*)(src + fl);
            }
            BARRIER_LGKM();
        }

        {
            const int slot = (h < 10) ? h : h - 10;
            const int c = 2 * tid;
            f2 s;
            s[0] = col_lds[pp][0][c]     + col_lds[pp][1][c]
                 + col_lds[pp][2][c]     + col_lds[pp][3][c];
            s[1] = col_lds[pp][0][c + 1] + col_lds[pp][1][c + 1]
                 + col_lds[pp][2][c + 1] + col_lds[pp][3][c + 1];
            *(f2*)&colstage[slot][c] = s;
        }
    }

    BARRIER_LGKM();   // colstage slots (heads 10..19) + rowstage complete

    // ---- flush heads 10..19 (slots 0..9) -> colpart
    {
        float* __restrict__ dst = colpart + ((size_t)t * NF + fbase + 10) * SEQ;
        const float* __restrict__ src = &colstage[0][0];
        #pragma unroll
        for (int it = 0; it < 5; ++it) {
            const int fl = (it * 256 + tid) * 4;
            *(f4*)(dst + fl) = *(const f4*)(src + fl);
        }
    }
    // ---- flush rowstage -> rowsum (16 consecutive floats per head)
    #pragma unroll
    for (int it = 0; it < 2; ++it) {
        const int e = it * 256 + tid;
        if (e < GH * RT) {
            const int h = e >> 4, r = e & 15;
            rowsum[((size_t)(fbase + h) << 9) + t * RT + r] = rowstage[h][r];
        }
    }
    // ---- flush WApart (write-once, float4 coalesced)
    float* __restrict__ wp = WApart + (size_t)g * SEQ * SEQ;
    #pragma unroll
    for (int rr = 0; rr < 4; ++rr) {
        f4 o0 = {wa_acc[rr][0], wa_acc[rr][1], wa_acc[rr][2], wa_acc[rr][3]};
        f4 o1 = {wa_acc[rr][4], wa_acc[rr][5], wa_acc[rr][6], wa_acc[rr][7]};
        *(f4*)(wp + ((size_t)(row0 + rr) << 9) + 4 * lane) = o0;
        *(f4*)(wp + ((size_t)(row0 + rr) << 9) + 256 + 4 * lane) = o1;
    }
}

// ---------------- Kernel 2 (merged): WA-reduce + per-head a1/a12/scale --------
__global__ __launch_bounds__(512) void kernel2(
    const float* __restrict__ WApart, float* __restrict__ WA,
    const float* __restrict__ rowsum, const float* __restrict__ colpart,
    const int* __restrict__ tokens, const float* __restrict__ weight,
    float* __restrict__ a1, float* __restrict__ sfac)
{
    __shared__ float part[8];
    const int b = blockIdx.x, tid = threadIdx.x;
    if (b < 128) {
        const size_t idx4 = (size_t)b * 512 + tid;     // float4 index, 65536 total
        f4 a = *(const f4*)(WApart + 4 * idx4);
        #pragma unroll 8
        for (int g = 1; g < NG; ++g) {
            f4 x = *(const f4*)(WApart + (size_t)g * (SEQ * SEQ) + 4 * idx4);
            a += x;
        }
        *(f4*)(WA + 4 * idx4) = a;
    } else {
        const int f = b - 128, j = tid;
        float cs = 0.f;
        #pragma unroll 8
        for (int t = 0; t < NT_; ++t)
            cs += colpart[((size_t)t * NF + f) * SEQ + j];
        const float m = (j >= 1 && j <= SEQ - 2 && tokens[j] != EOSI) ? 1.f : 0.f;
        const float v = m * (rowsum[((size_t)f << 9) + j] + cs);
        a1[((size_t)f << 9) + j] = v;
        float s = v;
        #pragma unroll
        for (int off = 32; off > 0; off >>= 1)
            s += __shfl_down(s, off, 64);
        const int wave = tid >> 6, lane = tid & 63;
        if (lane == 0) part[wave] = s;
        __syncthreads();
        if (tid == 0) {
            float a12 = 0.f;
            #pragma unroll
            for (int k = 0; k < 8; ++k) a12 += part[k];
            sfac[f] = weight[f] / a12;
        }
    }
}

// ---------------- Pass 3: rank-660 outer-product + WA + sigmoid ----------------
// grid (32,32) = 1024 blocks; 16x16 output tile, 1 output/thread; 32-f chunks
__global__ __launch_bounds__(256) void pass3_kernel(
    const float* __restrict__ WA, const float* __restrict__ a1,
    const float* __restrict__ sfac, const int* __restrict__ tokens,
    const float* __restrict__ bias, float* __restrict__ out)
{
    const int TI = blockIdx.y * 16;
    const int TJ = blockIdx.x * 16;
    const int tid = threadIdx.x;
    const int tx = tid & 15, ty = tid >> 4;

    __shared__ float u_s[32][17];
    __shared__ float v_s[32][17];

    float acc = 0.f;

    for (int f0 = 0; f0 < NF; f0 += 32) {
        #pragma unroll
        for (int c = 0; c < 4; ++c) {
            const int e = c * 256 + tid;        // 0..1023
            const int arr = e >> 9, ff = (e >> 4) & 31, ii = e & 15;
            const int f = f0 + ff;
            float val = 0.f;
            if (f < NF) {
                if (arr == 0) {
                    int Iu = TI + 1 + ii; if (Iu > SEQ - 1) Iu = SEQ - 1;
                    val = a1[((size_t)f << 9) + Iu] * sfac[f];
                } else {
                    int Ju = TJ + 1 + ii; if (Ju > SEQ - 1) Ju = SEQ - 1;
                    val = a1[((size_t)f << 9) + Ju];
                }
            }
            if (arr == 0) u_s[ff][ii] = val; else v_s[ff][ii] = val;
        }
        __syncthreads();
        #pragma unroll
        for (int ff = 0; ff < 32; ++ff)
            acc += u_s[ff][ty] * v_s[ff][tx];
        __syncthreads();
    }

    const int i = TI + ty, j = TJ + tx;
    if (i < CROP && j < CROP) {
        const int I = i + 1, J = j + 1;
        const float mi = (tokens[I] != EOSI) ? 1.f : 0.f;
        const float mj = (tokens[J] != EOSI) ? 1.f : 0.f;
        const float first = mi * mj * (WA[((size_t)I << 9) + J] + WA[((size_t)J << 9) + I]);
        const float logit = first - acc + bias[0];
        out[(size_t)i * CROP + j] = 1.f / (1.f + expf(-logit));
    }
}

extern "C" void kernel_launch(void* const* d_in, const int* in_sizes, int n_in,
                              void* d_out, int out_size, void* d_ws, size_t ws_size,
                              hipStream_t stream) {
    const int*   tokens = (const int*)d_in[0];
    const float* A      = (const float*)d_in[1];
    const float* weight = (const float*)d_in[2];
    const float* bias   = (const float*)d_in[3];
    float* out = (float*)d_out;

    // workspace (floats), all write-once, no zeroing:
    // WApart[33*512*512] | colpart[32*660*512] | WA[512*512] | rowsum[660*512] | a1[660*512] | sfac[660]
    float* WApart  = (float*)d_ws;
    float* colpart = WApart + (size_t)NG * SEQ * SEQ;
    float* WA      = colpart + (size_t)NT_ * NF * SEQ;
    float* rowsum  = WA + (size_t)SEQ * SEQ;
    float* a1      = rowsum + (size_t)NF * SEQ;
    float* sfac    = a1 + (size_t)NF * SEQ;

    dim3 g1(NT_, NG);   // 32 x 33
    pass1_kernel<<<g1, 256, 0, stream>>>(A, tokens, weight, WApart, rowsum, colpart);

    kernel2<<<128 + NF, 512, 0, stream>>>(WApart, WA, rowsum, colpart, tokens, weight, a1, sfac);

    dim3 g3(32, 32);
    pass3_kernel<<<g3, 256, 0, stream>>>(WA, a1, sfac, tokens, bias, out);
}

// Round 11
// 214.679 us; speedup vs baseline: 1.6703x; 1.1324x over previous
//
#include <hip/hip_runtime.h>
#include <math.h>

// Problem constants (B=1, LAYERS=33, HEADS=20, SEQ=512)
#define SEQ   512
#define NF    660
#define CROP  510
#define EOSI  2
#define RT    16           // rows per block (pass1)
#define GH    20           // heads per group (pass1)
#define NT_   32           // row tiles
#define NG    33           // head groups

typedef float f4 __attribute__((ext_vector_type(4)));

// load one batch (4 rows x wave's 128-col strip): two f4 per lane
#define LOADB(d0, d1, ptr) do {                                               \
    d0 = *(const f4*)(ptr);                                                   \
    d1 = *(const f4*)((ptr) + 64);                                            \
} while (0)

// consume one batch b: WA acc, masked row-sum partial (butterfly over c8),
// masked col-sum acc. NO barrier, NO global store.
#define CONS(x0, x1, b, h) do {                                               \
    float vals[8] = {x0[0], x0[1], x0[2], x0[3],                              \
                     x1[0], x1[1], x1[2], x1[3]};                             \
    float rs = 0.f;                                                           \
    const float mb = mrow[b];                                                 \
    _Pragma("unroll")                                                         \
    for (int e = 0; e < 8; ++e) {                                             \
        const float v = vals[e];                                              \
        wa_acc[b][e] += wf * v;                                               \
        rs += mskv[e] * v;                                                    \
        cacc[e] += mb * v;                                                    \
    }                                                                         \
    rs += __shfl_xor(rs, 1, 64);                                              \
    rs += __shfl_xor(rs, 2, 64);                                              \
    rs += __shfl_xor(rs, 4, 64);                                              \
    rs += __shfl_xor(rs, 8, 64);                                              \
    if (c8 == 0) rowpart[h][(b) * 4 + r][wave] = rs;                          \
} while (0)

// ---------------- Pass 1: stream 692MB, barrier-free hot loop ----------------
// grid (32 row-tiles, 33 head-groups), block 256 (4 waves).
// Wave w owns cols [128w,128w+128) for all 16 rows -> col-sum needs NO
// cross-wave combine; row-sum partials go to a 5KB LDS array reduced at end.
// Hot loop: zero barriers, zero global stores, waves fully independent.
// LDS 47KB -> 3 blocks/CU = 12 waves/CU; lean VGPR (~100), no bounds gamble.
__global__ __launch_bounds__(256) void pass1_kernel(
    const float* __restrict__ A, const int* __restrict__ tokens,
    const float* __restrict__ weight,
    float* __restrict__ WApart, float* __restrict__ rowsum, float* __restrict__ colpart)
{
    __shared__ float msk[SEQ];                // 2 KB
    __shared__ float colstage[GH][SEQ];       // 40 KB, wave-exclusive 128-col strips
    __shared__ float rowpart[GH][RT][4];      // 5 KB per-wave row partials

    const int t = blockIdx.x, g = blockIdx.y;
    const int tid = threadIdx.x, wave = tid >> 6, lane = tid & 63;
    const int r = lane >> 4, c8 = lane & 15;
    const int fbase = g * GH;
    const int row0 = t * RT;
    const int col0 = wave * 128;

    for (int j = tid; j < SEQ; j += 256)
        msk[j] = (j >= 1 && j <= SEQ - 2 && tokens[j] != EOSI) ? 1.f : 0.f;
    __syncthreads();

    float mskv[8];
    #pragma unroll
    for (int p = 0; p < 2; ++p)
        #pragma unroll
        for (int k = 0; k < 4; ++k)
            mskv[p * 4 + k] = msk[col0 + p * 64 + c8 * 4 + k];
    float mrow[4];
    #pragma unroll
    for (int b = 0; b < 4; ++b) mrow[b] = msk[row0 + b * 4 + r];

    float wa_acc[4][8];
    #pragma unroll
    for (int b = 0; b < 4; ++b)
        #pragma unroll
        for (int e = 0; e < 8; ++e) wa_acc[b][e] = 0.f;

    // per-lane offset within a head: (row0 + r)*512 + col0 + c8*4
    const size_t lofs = (size_t)(row0 + r) * SEQ + col0 + c8 * 4;

    f4 a0, a1, b0, b1;
    {   // prime: head 0, batch 0
        const float* Ah = A + ((size_t)fbase << 18) + lofs;
        LOADB(a0, a1, Ah);
    }

    #pragma unroll 1
    for (int h = 0; h < GH; ++h) {
        const float wf = weight[fbase + h];
        const float* __restrict__ Ah = A + ((size_t)(fbase + h) << 18) + lofs;
        float cacc[8] = {0, 0, 0, 0, 0, 0, 0, 0};

        LOADB(b0, b1, Ah + 2048);             // batch 1
        CONS(a0, a1, 0, h);
        LOADB(a0, a1, Ah + 4096);             // batch 2
        CONS(b0, b1, 1, h);
        LOADB(b0, b1, Ah + 6144);             // batch 3
        CONS(a0, a1, 2, h);
        if (h < GH - 1) LOADB(a0, a1, Ah + 262144);   // next head, batch 0
        CONS(b0, b1, 3, h);

        // col-sum: butterfly across the 4 r-groups (within wave), then write
        // this wave's exclusive 128-col strip of colstage[h]
        #pragma unroll
        for (int e = 0; e < 8; ++e) {
            cacc[e] += __shfl_xor(cacc[e], 16, 64);
            cacc[e] += __shfl_xor(cacc[e], 32, 64);
        }
        if (r == 0) {
            f4 s = {cacc[0], cacc[1], cacc[2], cacc[3]};
            *(f4*)&colstage[h][col0 + c8 * 4] = s;
        } else if (r == 1) {
            f4 s = {cacc[4], cacc[5], cacc[6], cacc[7]};
            *(f4*)&colstage[h][col0 + 64 + c8 * 4] = s;
        }
    }

    __syncthreads();   // all waves' colstage strips + rowpart complete

    // ---- flush colstage -> colpart: 20 heads x 512 cols contiguous (40 KB)
    {
        float* __restrict__ dst = colpart + ((size_t)t * NF + fbase) * SEQ;
        const float* __restrict__ src = &colstage[0][0];
        #pragma unroll
        for (int it = 0; it < 10; ++it) {
            const int fl = (it * 256 + tid) * 4;
            *(f4*)(dst + fl) = *(const f4*)(src + fl);
        }
    }
    // ---- reduce rowpart (4 wave-strips) -> rowsum
    // GH*RT = 320 entries > 256 threads: MUST loop (R10 bug: single if dropped
    // entries 256..319 -> heads 16..19 poisoned)
    #pragma unroll
    for (int it = 0; it < 2; ++it) {
        const int e = it * 256 + tid;
        if (e < GH * RT) {
            const int h = e >> 4, i = e & 15;
            rowsum[((size_t)(fbase + h) << 9) + row0 + i] =
                rowpart[h][i][0] + rowpart[h][i][1] + rowpart[h][i][2] + rowpart[h][i][3];
        }
    }
    // ---- flush WApart (write-once, f4 coalesced; wave-exclusive col strips)
    {
        float* __restrict__ wp = WApart + (size_t)g * SEQ * SEQ + lofs;
        #pragma unroll
        for (int b = 0; b < 4; ++b) {
            f4 o0 = {wa_acc[b][0], wa_acc[b][1], wa_acc[b][2], wa_acc[b][3]};
            f4 o1 = {wa_acc[b][4], wa_acc[b][5], wa_acc[b][6], wa_acc[b][7]};
            float* dst = wp + (size_t)b * 4 * SEQ;
            *(f4*)dst = o0;
            *(f4*)(dst + 64) = o1;
        }
    }
}

// ---------------- Kernel 2 (merged): WA-reduce + per-head a1/a12/scale --------
__global__ __launch_bounds__(512) void kernel2(
    const float* __restrict__ WApart, float* __restrict__ WA,
    const float* __restrict__ rowsum, const float* __restrict__ colpart,
    const int* __restrict__ tokens, const float* __restrict__ weight,
    float* __restrict__ a1, float* __restrict__ sfac)
{
    __shared__ float part[8];
    const int b = blockIdx.x, tid = threadIdx.x;
    if (b < 128) {
        const size_t idx4 = (size_t)b * 512 + tid;     // float4 index, 65536 total
        f4 a = *(const f4*)(WApart + 4 * idx4);
        #pragma unroll 8
        for (int g = 1; g < NG; ++g) {
            f4 x = *(const f4*)(WApart + (size_t)g * (SEQ * SEQ) + 4 * idx4);
            a += x;
        }
        *(f4*)(WA + 4 * idx4) = a;
    } else {
        const int f = b - 128, j = tid;
        float cs = 0.f;
        #pragma unroll 8
        for (int t = 0; t < NT_; ++t)
            cs += colpart[((size_t)t * NF + f) * SEQ + j];
        const float m = (j >= 1 && j <= SEQ - 2 && tokens[j] != EOSI) ? 1.f : 0.f;
        const float v = m * (rowsum[((size_t)f << 9) + j] + cs);
        a1[((size_t)f << 9) + j] = v;
        float s = v;
        #pragma unroll
        for (int off = 32; off > 0; off >>= 1)
            s += __shfl_down(s, off, 64);
        const int wave = tid >> 6, lane = tid & 63;
        if (lane == 0) part[wave] = s;
        __syncthreads();
        if (tid == 0) {
            float a12 = 0.f;
            #pragma unroll
            for (int k = 0; k < 8; ++k) a12 += part[k];
            sfac[f] = weight[f] / a12;
        }
    }
}

// ---------------- Pass 3: rank-660 outer-product + WA + sigmoid ----------------
// grid (32,32) = 1024 blocks; 16x16 output tile, 1 output/thread; 32-f chunks
__global__ __launch_bounds__(256) void pass3_kernel(
    const float* __restrict__ WA, const float* __restrict__ a1,
    const float* __restrict__ sfac, const int* __restrict__ tokens,
    const float* __restrict__ bias, float* __restrict__ out)
{
    const int TI = blockIdx.y * 16;
    const int TJ = blockIdx.x * 16;
    const int tid = threadIdx.x;
    const int tx = tid & 15, ty = tid >> 4;

    __shared__ float u_s[32][17];
    __shared__ float v_s[32][17];

    float acc = 0.f;

    for (int f0 = 0; f0 < NF; f0 += 32) {
        #pragma unroll
        for (int c = 0; c < 4; ++c) {
            const int e = c * 256 + tid;        // 0..1023
            const int arr = e >> 9, ff = (e >> 4) & 31, ii = e & 15;
            const int f = f0 + ff;
            float val = 0.f;
            if (f < NF) {
                if (arr == 0) {
                    int Iu = TI + 1 + ii; if (Iu > SEQ - 1) Iu = SEQ - 1;
                    val = a1[((size_t)f << 9) + Iu] * sfac[f];
                } else {
                    int Ju = TJ + 1 + ii; if (Ju > SEQ - 1) Ju = SEQ - 1;
                    val = a1[((size_t)f << 9) + Ju];
                }
            }
            if (arr == 0) u_s[ff][ii] = val; else v_s[ff][ii] = val;
        }
        __syncthreads();
        #pragma unroll
        for (int ff = 0; ff < 32; ++ff)
            acc += u_s[ff][ty] * v_s[ff][tx];
        __syncthreads();
    }

    const int i = TI + ty, j = TJ + tx;
    if (i < CROP && j < CROP) {
        const int I = i + 1, J = j + 1;
        const float mi = (tokens[I] != EOSI) ? 1.f : 0.f;
        const float mj = (tokens[J] != EOSI) ? 1.f : 0.f;
        const float first = mi * mj * (WA[((size_t)I << 9) + J] + WA[((size_t)J << 9) + I]);
        const float logit = first - acc + bias[0];
        out[(size_t)i * CROP + j] = 1.f / (1.f + expf(-logit));
    }
}

extern "C" void kernel_launch(void* const* d_in, const int* in_sizes, int n_in,
                              void* d_out, int out_size, void* d_ws, size_t ws_size,
                              hipStream_t stream) {
    const int*   tokens = (const int*)d_in[0];
    const float* A      = (const float*)d_in[1];
    const float* weight = (const float*)d_in[2];
    const float* bias   = (const float*)d_in[3];
    float* out = (float*)d_out;

    // workspace (floats), all write-once, no zeroing:
    // WApart[33*512*512] | colpart[32*660*512] | WA[512*512] | rowsum[660*512] | a1[660*512] | sfac[660]
    float* WApart  = (float*)d_ws;
    float* colpart = WApart + (size_t)NG * SEQ * SEQ;
    float* WA      = colpart + (size_t)NT_ * NF * SEQ;
    float* rowsum  = WA + (size_t)SEQ * SEQ;
    float* a1      = rowsum + (size_t)NF * SEQ;
    float* sfac    = a1 + (size_t)NF * SEQ;

    dim3 g1(NT_, NG);   // 32 x 33
    pass1_kernel<<<g1, 256, 0, stream>>>(A, tokens, weight, WApart, rowsum, colpart);

    kernel2<<<128 + NF, 512, 0, stream>>>(WApart, WA, rowsum, colpart, tokens, weight, a1, sfac);

    dim3 g3(32, 32);
    pass3_kernel<<<g3, 256, 0, stream>>>(WA, a1, sfac, tokens, bias, out);
}